// Round 11
// baseline (91.597 us; speedup 1.0000x reference)
//
#include <hip/hip_runtime.h>
#include <math.h>

constexpr int N     = 8192;
constexpr int K     = 30;
constexpr int TPB   = 512;                // pair block: 8 waves
constexpr int IPT   = 4;                  // i-rows per thread
constexpr int ISPAN = TPB * IPT;          // 2048 i per block
constexpr int NIC   = N / ISPAN;          // 4 i-chunks
constexpr int NJ    = 64;                 // j-slices
constexpr int JSPAN = N / NJ;             // 128 j per block
constexpr int NBLK  = NIC * NJ;           // 256 blocks -> 1 per CU, all resident
constexpr int MTPB  = 256;                // mrl/final block size

// d_ws layout:
//   [0, 32768)        float   mrl[N]
//   [32768, 34816)    double  pnum[NBLK]
//   [34816, 35840)    int     pcnt[NBLK]

__global__ void mrl_kernel(const float* __restrict__ est,
                           const float* __restrict__ intervals,
                           float* __restrict__ mrl) {
    __shared__ float s_est[MTPB * K];     // this block's 256 rows, 30 KB

    const int tid  = threadIdx.x;
    const int row0 = blockIdx.x * MTPB;

    // coalesced staging: 256x30 floats = 3840 float2, 15 per thread
    const float2* src = (const float2*)(est + (size_t)row0 * K);
    float2* dst = (float2*)s_est;
#pragma unroll
    for (int t = 0; t < (MTPB * K) / (2 * MTPB); ++t)   // 15
        dst[t * MTPB + tid] = src[t * MTPB + tid];
    __syncthreads();

    const float* e = s_est + tid * K;
    double sp = 1.0, m = 0.0;             // f64 accumulation (proven R4/R5)
#pragma unroll
    for (int k = 0; k < K; ++k) {
        float hf = 1.0f / (1.0f + __expf(-e[k]));   // hardware v_exp_f32
        double h = (double)hf;
        m += (double)intervals[k] * h * sp;
        sp *= (1.0 - h);
    }
    mrl[row0 + tid] = (float)m;
}

__global__ void __launch_bounds__(TPB, 4)   // cap 128 VGPR: ~60 live, NO spill
pair_kernel(const float* __restrict__ target,
            const float* __restrict__ mrl,
            double* __restrict__ pnum,
            int* __restrict__ pcnt) {
    __shared__ __align__(16) float s_t[JSPAN];
    __shared__ __align__(16) float s_m[JSPAN];
    __shared__ double r_num[TPB];
    __shared__ int    r_cnt[TPB];

    const int tid = threadIdx.x;
    const int bid = blockIdx.x;
    const int ic  = bid >> 6;             // i-chunk (of 2048 rows)
    const int js  = bid & (NJ - 1);       // j-slice

    // each thread owns 4 i-rows at stride TPB (coalesced loads)
    float ti[IPT]; float mi[IPT]; bool ev[IPT];
#pragma unroll
    for (int k = 0; k < IPT; ++k) {
        const int i = ic * ISPAN + k * TPB + tid;
        const float2 tv = ((const float2*)target)[i];
        ti[k] = tv.x;
        ev[k] = (tv.y != 0.0f);
        mi[k] = mrl[i];
    }

    if (tid < JSPAN) {
        const int j = js * JSPAN + tid;
        s_t[tid] = ((const float2*)target)[j].x;
        s_m[tid] = mrl[j];
    }
    __syncthreads();

    const float4* s_t4 = (const float4*)s_t;
    const float4* s_m4 = (const float4*)s_m;

    double smj[IPT];                      // f64 chunk accumulators
    int    cc[IPT];
#pragma unroll
    for (int k = 0; k < IPT; ++k) { smj[k] = 0.0; cc[k] = 0; }

#pragma unroll
    for (int ch = 0; ch < JSPAN / 64; ++ch) {        // 2 chunks of 64 j
        float a[IPT][4];
        int   c[IPT][4];
#pragma unroll
        for (int k = 0; k < IPT; ++k)
#pragma unroll
            for (int q = 0; q < 4; ++q) { a[k][q] = 0.0f; c[k][q] = 0; }

#pragma unroll
        for (int q = 0; q < 16; ++q) {               // 16 x 4 j
            const int jj4 = ch * 16 + q;
            // broadcast ds_read_b128 (uniform address) -> conflict-free;
            // each read pair feeds 16 pair-updates (4 i-rows)
            const float4 tv = s_t4[jj4];
            const float4 mv = s_m4[jj4];
#pragma unroll
            for (int k = 0; k < IPT; ++k) {
                const bool b0 = ti[k] < tv.x, b1 = ti[k] < tv.y,
                           b2 = ti[k] < tv.z, b3 = ti[k] < tv.w;
                c[k][0] += b0; a[k][0] += b0 ? mv.x : 0.0f;
                c[k][1] += b1; a[k][1] += b1 ? mv.y : 0.0f;
                c[k][2] += b2; a[k][2] += b2 ? mv.z : 0.0f;
                c[k][3] += b3; a[k][3] += b3 ? mv.w : 0.0f;
            }
        }
#pragma unroll
        for (int k = 0; k < IPT; ++k) {              // flush every 64 pairs
            smj[k] += (double)((a[k][0] + a[k][1]) + (a[k][2] + a[k][3]));
            cc[k]  += (c[k][0] + c[k][1]) + (c[k][2] + c[k][3]);
        }
    }

    double num = 0.0;
    int    cnt = 0;
#pragma unroll
    for (int k = 0; k < IPT; ++k) {
        if (ev[k]) {
            num += (double)cc[k] * (double)mi[k] - smj[k];
            cnt += cc[k];
        }
    }

    r_num[tid] = num;
    r_cnt[tid] = cnt;
    __syncthreads();
    for (int s = TPB / 2; s > 0; s >>= 1) {
        if (tid < s) {
            r_num[tid] += r_num[tid + s];
            r_cnt[tid] += r_cnt[tid + s];
        }
        __syncthreads();
    }
    if (tid == 0) {
        pnum[bid] = r_num[0];
        pcnt[bid] = r_cnt[0];
    }
}

__global__ void final_kernel(const double* __restrict__ pnum,
                             const int* __restrict__ pcnt,
                             float* __restrict__ out) {
    __shared__ double r_num[MTPB];
    __shared__ int    r_cnt[MTPB];
    const int tid = threadIdx.x;
    // NBLK == MTPB: one partial per thread, fixed order -> deterministic
    r_num[tid] = pnum[tid];
    r_cnt[tid] = pcnt[tid];
    __syncthreads();
    for (int s = MTPB / 2; s > 0; s >>= 1) {
        if (tid < s) {
            r_num[tid] += r_num[tid + s];
            r_cnt[tid] += r_cnt[tid + s];
        }
        __syncthreads();
    }
    if (tid == 0) out[0] = (float)(r_num[0] / (double)r_cnt[0]);
}

extern "C" void kernel_launch(void* const* d_in, const int* in_sizes, int n_in,
                              void* d_out, int out_size, void* d_ws, size_t ws_size,
                              hipStream_t stream) {
    const float* est       = (const float*)d_in[0];   // (N, K) fp32
    const float* target    = (const float*)d_in[1];   // (N, 2) fp32
    const float* intervals = (const float*)d_in[2];   // (K,)  fp32
    float* out = (float*)d_out;

    float*  mrl  = (float*)d_ws;
    double* pnum = (double*)((char*)d_ws + 32768);
    int*    pcnt = (int*)((char*)d_ws + 34816);

    mrl_kernel<<<N / MTPB, MTPB, 0, stream>>>(est, intervals, mrl);
    pair_kernel<<<NBLK, TPB, 0, stream>>>(target, mrl, pnum, pcnt);
    final_kernel<<<1, MTPB, 0, stream>>>(pnum, pcnt, out);
}

// Round 12
// 20.520 us; speedup vs baseline: 4.4638x; 4.4638x over previous
//
#include <hip/hip_runtime.h>
#include <math.h>

constexpr int N     = 8192;
constexpr int K     = 30;
constexpr int TPB   = 1024;               // pair block: 16 waves, 1 block/CU
constexpr int NI    = N / TPB;            // 8 i-chunks (IPT=1)
constexpr int NJ    = 32;                 // j-slices
constexpr int JSPAN = N / NJ;             // 256 j per block (same as R5 body)
constexpr int NBLK  = NI * NJ;            // 256 blocks total (4x fewer than R5)
constexpr int MB    = 128;                // mrl block size
constexpr int FTPB  = 256;                // final block size (== NBLK partials)

// d_ws layout:
//   [0, 32768)        float   mrl[N]
//   [32768, 34816)    double  pnum[NBLK]
//   [34816, 35840)    int     pcnt[NBLK]

__global__ void mrl_kernel(const float* __restrict__ est,
                           const float* __restrict__ intervals,
                           float* __restrict__ mrl) {
    __shared__ float s_est[MB * K];       // this block's 128 rows, 15 KB

    const int tid  = threadIdx.x;
    const int row0 = blockIdx.x * MB;

    // coalesced staging: 128x30 floats = 1920 float2, 15 per thread
    const float2* src = (const float2*)(est + (size_t)row0 * K);
    float2* dst = (float2*)s_est;
#pragma unroll
    for (int t = 0; t < K / 2; ++t)       // 15
        dst[t * MB + tid] = src[t * MB + tid];
    __syncthreads();

    const float* e = s_est + tid * K;
    double sp = 1.0, m = 0.0;             // f64 accumulation (proven R4/R5)
#pragma unroll
    for (int k = 0; k < K; ++k) {
        float hf = 1.0f / (1.0f + __expf(-e[k]));   // hardware v_exp_f32
        double h = (double)hf;
        m += (double)intervals[k] * h * sp;
        sp *= (1.0 - h);
    }
    mrl[row0 + tid] = (float)m;
}

__global__ void pair_kernel(const float* __restrict__ target,
                            const float* __restrict__ mrl,
                            double* __restrict__ pnum,
                            int* __restrict__ pcnt) {
    __shared__ __align__(16) float s_t[JSPAN];
    __shared__ __align__(16) float s_m[JSPAN];
    __shared__ double r_num[TPB];
    __shared__ int    r_cnt[TPB];

    const int tid = threadIdx.x;
    const int bid = blockIdx.x;
    const int ib  = bid >> 5;             // i-chunk (of 1024 rows)
    const int js  = bid & (NJ - 1);       // j-slice
    const int i   = ib * TPB + tid;

    const float2 ti2 = ((const float2*)target)[i];
    const float  ti  = ti2.x;
    const bool   ei  = (ti2.y != 0.0f);
    const float  mi  = mrl[i];

    if (tid < JSPAN) {
        const int j = js * JSPAN + tid;
        s_t[tid] = ((const float2*)target)[j].x;
        s_m[tid] = mrl[j];
    }
    __syncthreads();

    // === R5's proven 20-VGPR inner loop, verbatim ===
    const float4* s_t4 = (const float4*)s_t;
    const float4* s_m4 = (const float4*)s_m;

    double smj = 0.0;                     // f64 chunk accumulator
    int c0 = 0, c1 = 0, c2 = 0, c3 = 0;

#pragma unroll
    for (int ch = 0; ch < JSPAN / 64; ++ch) {        // 4 chunks of 64 j
        float a0 = 0.f, a1 = 0.f, a2 = 0.f, a3 = 0.f;
#pragma unroll
        for (int q = 0; q < 16; ++q) {               // 16 x 4 j
            const int jj4 = ch * 16 + q;
            // broadcast ds_read_b128 (uniform address) -> conflict-free
            float4 tv = s_t4[jj4];
            float4 mv = s_m4[jj4];
            bool b0 = ti < tv.x, b1 = ti < tv.y, b2 = ti < tv.z, b3 = ti < tv.w;
            c0 += b0; a0 += b0 ? mv.x : 0.0f;
            c1 += b1; a1 += b1 ? mv.y : 0.0f;
            c2 += b2; a2 += b2 ? mv.z : 0.0f;
            c3 += b3; a3 += b3 ? mv.w : 0.0f;
        }
        smj += (double)((a0 + a1) + (a2 + a3));      // flush every 64 pairs
    }

    const int cnt = (c0 + c1) + (c2 + c3);
    r_num[tid] = ei ? ((double)cnt * (double)mi - smj) : 0.0;
    r_cnt[tid] = ei ? cnt : 0;
    __syncthreads();
    for (int s = TPB / 2; s > 0; s >>= 1) {
        if (tid < s) {
            r_num[tid] += r_num[tid + s];
            r_cnt[tid] += r_cnt[tid + s];
        }
        __syncthreads();
    }
    if (tid == 0) {
        pnum[bid] = r_num[0];
        pcnt[bid] = r_cnt[0];
    }
}

__global__ void final_kernel(const double* __restrict__ pnum,
                             const int* __restrict__ pcnt,
                             float* __restrict__ out) {
    __shared__ double r_num[FTPB];
    __shared__ int    r_cnt[FTPB];
    const int tid = threadIdx.x;
    // NBLK == FTPB: one partial per thread, fixed order -> deterministic
    r_num[tid] = pnum[tid];
    r_cnt[tid] = pcnt[tid];
    __syncthreads();
    for (int s = FTPB / 2; s > 0; s >>= 1) {
        if (tid < s) {
            r_num[tid] += r_num[tid + s];
            r_cnt[tid] += r_cnt[tid + s];
        }
        __syncthreads();
    }
    if (tid == 0) out[0] = (float)(r_num[0] / (double)r_cnt[0]);
}

extern "C" void kernel_launch(void* const* d_in, const int* in_sizes, int n_in,
                              void* d_out, int out_size, void* d_ws, size_t ws_size,
                              hipStream_t stream) {
    const float* est       = (const float*)d_in[0];   // (N, K) fp32
    const float* target    = (const float*)d_in[1];   // (N, 2) fp32
    const float* intervals = (const float*)d_in[2];   // (K,)  fp32
    float* out = (float*)d_out;

    float*  mrl  = (float*)d_ws;
    double* pnum = (double*)((char*)d_ws + 32768);
    int*    pcnt = (int*)((char*)d_ws + 34816);

    mrl_kernel<<<N / MB, MB, 0, stream>>>(est, intervals, mrl);
    pair_kernel<<<NBLK, TPB, 0, stream>>>(target, mrl, pnum, pcnt);
    final_kernel<<<1, FTPB, 0, stream>>>(pnum, pcnt, out);
}